// Round 1
// baseline (129.745 us; speedup 1.0000x reference)
//
#include <hip/hip_runtime.h>

constexpr int SLN = 512, BSZ = 128, TAG = 32;
constexpr float INVLN2 = 1.4426950408889634f;
constexpr float LN2f = 0.6931471805599453f;

__device__ __forceinline__ float exp2_fast(float x) {
#if __has_builtin(__builtin_amdgcn_exp2f)
  return __builtin_amdgcn_exp2f(x);
#else
  return exp2f(x);
#endif
}
__device__ __forceinline__ float log2_fast(float x) {
#if __has_builtin(__builtin_amdgcn_logf)
  return __builtin_amdgcn_logf(x);
#else
  return log2f(x);
#endif
}
__device__ __forceinline__ float rdlane(float v, int l) {
  return __uint_as_float((unsigned)__builtin_amdgcn_readlane((int)__float_as_uint(v), l));
}

// Block b < BSZ: forward scan (log-partition) for batch b -> ws[b]
// Block b >= BSZ: gold-path score for batch b-BSZ        -> ws[BSZ + b]
__global__ __launch_bounds__(64) void crf_fwd_kernel(
    const float* __restrict__ emission, const int* __restrict__ length,
    const int* __restrict__ target, const float* __restrict__ transition,
    const float* __restrict__ start_tr, const float* __restrict__ end_tr,
    float* __restrict__ ws) {
  const int blk = blockIdx.x;
  const int lane = threadIdx.x;

  if (blk < BSZ) {
    const int b = blk;
    const int len = length[b];          // in [2, 512]
    const int j = lane & 31;            // lanes 32-63 mirror 0-31 (keeps readlane uniform)

    // E[i] = exp(transition[i][j]) = 2^(T*INVLN2), held in VGPRs (column j)
    float E[TAG];
#pragma unroll
    for (int i = 0; i < TAG; ++i)
      E[i] = exp2_fast(transition[i * TAG + j] * INVLN2);

    const float* emb = emission + (size_t)b * SLN * TAG + j;

    // alpha in linear base-2 domain: a = 2^(A - base)
    float a = exp2_fast((start_tr[j] + emb[0]) * INVLN2);
    float base = 0.f;

    // double-buffered emission prefetch, 8 steps ahead
    float buf0[8], buf1[8];
#pragma unroll
    for (int u = 0; u < 8; ++u) {
      int tp = 1 + u; tp = tp < SLN ? tp : SLN - 1;
      buf0[u] = emb[tp * TAG];
    }

    const int nblk = (len - 1 + 7) >> 3;   // len >= 2 so nblk >= 1
    for (int kb = 0; kb < nblk; ++kb) {
      const int t0 = 1 + (kb << 3);
      // prefetch next block's emissions (clamped addresses, always valid)
#pragma unroll
      for (int u = 0; u < 8; ++u) {
        int tp = t0 + 8 + u; tp = tp < SLN ? tp : SLN - 1;
        buf1[u] = emb[tp * TAG];
      }
#pragma unroll
      for (int u = 0; u < 8; ++u) {
        const int t = t0 + u;
        const float emf = exp2_fast(buf0[u] * INVLN2);  // off critical path
        float acc0 = 0.f, acc1 = 0.f;
#pragma unroll
        for (int i = 0; i < TAG; i += 2) {
          acc0 = fmaf(rdlane(a, i),     E[i],     acc0);
          acc1 = fmaf(rdlane(a, i + 1), E[i + 1], acc1);
        }
        const float anew = (acc0 + acc1) * emf;
        a = (t < len) ? anew : a;        // identity step in the padded tail
      }
      // exact power-of-two renorm once per 8 steps
      {
        const unsigned ab = (unsigned)__builtin_amdgcn_readlane((int)__float_as_uint(a), 0);
        const int e = (int)((ab >> 23) & 255u) - 127;
        const float scale = __int_as_float((127 - e) << 23);  // 2^-e, exact
        a *= scale;
        base += (float)e;                // integer-valued, exact in f32
      }
#pragma unroll
      for (int u = 0; u < 8; ++u) buf0[u] = buf1[u];
    }

    // log_partition = ln2 * (base + log2(sum_j a_j * 2^(end_j*INVLN2)))
    float v = a * exp2_fast(end_tr[j] * INVLN2);
#pragma unroll
    for (int m = 16; m >= 1; m >>= 1) v += __shfl_xor(v, m, 64);
    if (lane == 0) ws[b] = LN2f * (base + log2_fast(v));

  } else {
    const int b = blk - BSZ;
    const int len = length[b];
    const int* tg = target + b * SLN;
    float s = 0.f;
#pragma unroll
    for (int k0 = 0; k0 < SLN; k0 += 64) {
      const int k = k0 + lane;
      if (k < len) {
        const int tk = tg[k];
        s += emission[((size_t)b * SLN + k) * TAG + tk];
        if (k >= 1) s += transition[tg[k - 1] * TAG + tk];
      }
    }
#pragma unroll
    for (int m = 32; m >= 1; m >>= 1) s += __shfl_xor(s, m, 64);
    if (lane == 0) {
      s += start_tr[tg[0]] + end_tr[tg[len - 1]];
      ws[BSZ + b] = s;
    }
  }
}

__global__ __launch_bounds__(64) void crf_reduce_kernel(const float* __restrict__ ws,
                                                        float* __restrict__ out) {
  const int lane = threadIdx.x;
  float v = (ws[lane] - ws[BSZ + lane]) + (ws[lane + 64] - ws[BSZ + lane + 64]);
#pragma unroll
  for (int m = 32; m >= 1; m >>= 1) v += __shfl_xor(v, m, 64);
  if (lane == 0) out[0] = v;
}

extern "C" void kernel_launch(void* const* d_in, const int* in_sizes, int n_in,
                              void* d_out, int out_size, void* d_ws, size_t ws_size,
                              hipStream_t stream) {
  const float* emission   = (const float*)d_in[0];
  const int*   length     = (const int*)d_in[1];
  const int*   target     = (const int*)d_in[2];
  const float* transition = (const float*)d_in[3];
  const float* start_tr   = (const float*)d_in[4];
  const float* end_tr     = (const float*)d_in[5];
  float* ws = (float*)d_ws;   // 256 floats: [0,128) logZ, [128,256) score

  crf_fwd_kernel<<<2 * BSZ, 64, 0, stream>>>(emission, length, target, transition,
                                             start_tr, end_tr, ws);
  crf_reduce_kernel<<<1, 64, 0, stream>>>(ws, (float*)d_out);
}